// Round 10
// baseline (178.786 us; speedup 1.0000x reference)
//
#include <hip/hip_runtime.h>

#define IMG_W 1024
#define IMG_H 1024

typedef float v4f __attribute__((ext_vector_type(4)));

__device__ __forceinline__ float rowmask(int li) {
    return (li >= 1 && li <= IMG_H - 2) ? 1.f : 0.f;
}

__global__ __launch_bounds__(256) void dir_rhs_kernel(
    const float* __restrict__ u,
    const float* __restrict__ f,
    const float* __restrict__ wt,
    float* __restrict__ out)
{
    // 2048 blocks = 16 images * 128 eight-row groups; XCD-chunked bijective
    // swizzle (2048 % 8 == 0): consecutive groups stay on one XCD's L2.
    const int orig = blockIdx.x;
    const int tile = (orig & 7) * 256 + (orig >> 3);

    const int b    = tile >> 7;              // 128 groups per image
    const int g0   = (tile & 127) << 3;      // first output row of group
    const int tid  = threadIdx.x;            // 0..255
    const int wave = tid >> 6;               // 0..3
    const int lane = tid & 63;
    const int j0   = tid << 2;               // 4 columns per thread
    const size_t img = (size_t)b << 20;

    const float* ub = u + img;
    const float* fb = f + img;

    const bool le = (tid == 0);              // covers col 0
    const bool re = (tid == 255);            // covers col 1023

    const float w00 = wt[0], w01 = wt[1], w02 = wt[2];
    const float w10 = wt[3], w11 = wt[4], w12 = wt[5];
    const float w20 = wt[6], w21 = wt[7], w22 = wt[8];
    const float cof = (float)(-(1.0 / 1023.0) * (1.0 / 1023.0) / 4.0);

    // Double-buffered edge-exchange scratch (parity x wave x row-slot).
    __shared__ float ledge[2][4][4];
    __shared__ float redge[2][4][4];

    // ---- Prologue: rows g0-1 .. g0+2 + f rows g0, g0+1 ----
    v4f cu[4];                               // masked v rows (window)
    float lh[4], rh[4];                      // column halos for the window
    {
        v4f raw[4];
        #pragma unroll
        for (int k = 0; k < 4; k++) {
            const int li = g0 - 1 + k;
            const int rc = li < 0 ? 0 : (li > IMG_H - 1 ? IMG_H - 1 : li);
            raw[k] = *(const v4f*)(ub + (size_t)rc * IMG_W + j0);
        }
        #pragma unroll
        for (int k = 0; k < 4; k++) {
            v4f t = raw[k] * rowmask(g0 - 1 + k);
            if (le) t.x = 0.f;               // col 0 boundary in v
            if (re) t.w = 0.f;               // col 1023 boundary in v
            cu[k] = t;
        }
        if (lane == 0) {
            #pragma unroll
            for (int k = 0; k < 4; k++) ledge[1][wave][k] = cu[k].x;
        }
        if (lane == 63) {
            #pragma unroll
            for (int k = 0; k < 4; k++) redge[1][wave][k] = cu[k].w;
        }
        __syncthreads();
        #pragma unroll
        for (int k = 0; k < 4; k++) {
            float l = __shfl_up(cu[k].w, 1);
            float r = __shfl_down(cu[k].x, 1);
            if (lane == 0)  l = (wave == 0) ? 0.f : redge[1][wave - 1][k];
            if (lane == 63) r = (wave == 3) ? 0.f : ledge[1][wave + 1][k];
            lh[k] = l; rh[k] = r;
        }
    }
    v4f fcur0 = __builtin_nontemporal_load((const v4f*)(fb + (size_t)g0 * IMG_W + j0));
    v4f fcur1 = __builtin_nontemporal_load((const v4f*)(fb + (size_t)(g0 + 1) * IMG_W + j0));

    // ---- 4 software-pipelined row-pair iterations ----
    #pragma unroll
    for (int it = 0; it < 4; ++it) {
        const int i0 = g0 + 2 * it;          // output rows i0, i0+1

        // (1) Issue NEXT iteration's loads first: 2 u rows + 2 NT f rows.
        v4f nu0, nu1, nf0, nf1;
        if (it < 3) {
            const int l3 = i0 + 3;
            const int l4 = i0 + 4;
            const int c3 = l3 > IMG_H - 1 ? IMG_H - 1 : l3;
            const int c4 = l4 > IMG_H - 1 ? IMG_H - 1 : l4;
            nu0 = *(const v4f*)(ub + (size_t)c3 * IMG_W + j0);
            nu1 = *(const v4f*)(ub + (size_t)c4 * IMG_W + j0);
            nf0 = __builtin_nontemporal_load((const v4f*)(fb + (size_t)(i0 + 2) * IMG_W + j0));
            nf1 = __builtin_nontemporal_load((const v4f*)(fb + (size_t)(i0 + 3) * IMG_W + j0));
        }

        // (2) Compute + store the current row-pair from registers (covers the
        //     latency of the loads issued above).
        const float keep0 = (i0 >= 1 && i0 <= IMG_H - 2) ? 1.f : 0.f;
        const float keep1 = (i0 + 1 <= IMG_H - 2) ? 1.f : 0.f;

        auto stencil = [&](int k, v4f fv, float keep) -> v4f {
            const v4f n = cu[k], cc = cu[k + 1], s = cu[k + 2];
            float r0 = cof * fv.x
                     + w00 * lh[k]     + w01 * n.x  + w02 * n.y
                     + w10 * lh[k + 1] + w11 * cc.x + w12 * cc.y
                     + w20 * lh[k + 2] + w21 * s.x  + w22 * s.y;
            float r1 = cof * fv.y
                     + w00 * n.x  + w01 * n.y  + w02 * n.z
                     + w10 * cc.x + w11 * cc.y + w12 * cc.z
                     + w20 * s.x  + w21 * s.y  + w22 * s.z;
            float r2 = cof * fv.z
                     + w00 * n.y  + w01 * n.z  + w02 * n.w
                     + w10 * cc.y + w11 * cc.z + w12 * cc.w
                     + w20 * s.y  + w21 * s.z  + w22 * s.w;
            float r3 = cof * fv.w
                     + w00 * n.z  + w01 * n.w  + w02 * rh[k]
                     + w10 * cc.z + w11 * cc.w + w12 * rh[k + 1]
                     + w20 * s.z  + w21 * s.w  + w22 * rh[k + 2];
            r0 *= keep; r1 *= keep; r2 *= keep; r3 *= keep;
            if (le) r0 = 0.f;                // col 0 stays Dirichlet
            if (re) r3 = 0.f;                // col 1023 stays Dirichlet
            return (v4f){r0, r1, r2, r3};
        };

        const v4f o0 = stencil(0, fcur0, keep0);
        const v4f o1 = stencil(1, fcur1, keep1);

        float* ob = out + img + (size_t)i0 * IMG_W + j0;
        __builtin_nontemporal_store(o0, (v4f*)ob);
        __builtin_nontemporal_store(o1, (v4f*)(ob + IMG_W));

        // (3) Consume prefetched rows: mask, exchange edges, rotate window.
        if (it < 3) {
            const int p = it & 1;
            v4f t3 = nu0 * rowmask(i0 + 3);
            v4f t4 = nu1 * rowmask(i0 + 4);
            if (le) { t3.x = 0.f; t4.x = 0.f; }
            if (re) { t3.w = 0.f; t4.w = 0.f; }

            if (lane == 0)  { ledge[p][wave][0] = t3.x; ledge[p][wave][1] = t4.x; }
            if (lane == 63) { redge[p][wave][0] = t3.w; redge[p][wave][1] = t4.w; }
            __syncthreads();

            float l3 = __shfl_up(t3.w, 1),  r3 = __shfl_down(t3.x, 1);
            float l4 = __shfl_up(t4.w, 1),  r4 = __shfl_down(t4.x, 1);
            if (lane == 0) {
                l3 = (wave == 0) ? 0.f : redge[p][wave - 1][0];
                l4 = (wave == 0) ? 0.f : redge[p][wave - 1][1];
            }
            if (lane == 63) {
                r3 = (wave == 3) ? 0.f : ledge[p][wave + 1][0];
                r4 = (wave == 3) ? 0.f : ledge[p][wave + 1][1];
            }

            cu[0] = cu[2]; cu[1] = cu[3]; cu[2] = t3; cu[3] = t4;
            lh[0] = lh[2]; lh[1] = lh[3]; lh[2] = l3; lh[3] = l4;
            rh[0] = rh[2]; rh[1] = rh[3]; rh[2] = r3; rh[3] = r4;
            fcur0 = nf0;   fcur1 = nf1;
        }
    }
}

extern "C" void kernel_launch(void* const* d_in, const int* in_sizes, int n_in,
                              void* d_out, int out_size, void* d_ws, size_t ws_size,
                              hipStream_t stream) {
    const float* u  = (const float*)d_in[0];
    const float* f  = (const float*)d_in[1];
    const float* wt = (const float*)d_in[2];
    float* out = (float*)d_out;

    const int B = 16;
    dim3 grid(B * (IMG_H / 8));   // one block per (batch, 8-row group): 2048 blocks
    dim3 block(256);              // 256 threads * 4 cols = 1024-wide rows
    dir_rhs_kernel<<<grid, block, 0, stream>>>(u, f, wt, out);
}

// Round 11
// 167.679 us; speedup vs baseline: 1.0662x; 1.0662x over previous
//
#include <hip/hip_runtime.h>

#define IMG_W 1024
#define IMG_H 1024

typedef float v4f __attribute__((ext_vector_type(4)));

__global__ __launch_bounds__(256) void dir_rhs_kernel(
    const float* __restrict__ u,
    const float* __restrict__ f,
    const float* __restrict__ wt,
    float* __restrict__ out)
{
    // 16 images * 512 row-pairs = 8192 blocks, XCD-chunked bijective swizzle.
    const int orig = blockIdx.x;
    const int tile = (orig & 7) * 1024 + (orig >> 3);

    const int b    = tile >> 9;              // 512 row-pairs per image
    const int i0   = (tile & 511) << 1;      // output rows i0, i0+1
    const int tid  = threadIdx.x;            // 0..255
    const int wave = tid >> 6;               // 0..3
    const int lane = tid & 63;
    const int j0   = tid << 2;               // 4 columns per thread
    const size_t img = (size_t)b << 20;

    const float* ub = u + img;

    const bool le = (tid == 0);              // thread covering col 0
    const bool re = (tid == 255);            // thread covering col 1023

    // ---- ALL VMEM hoisted: 4 coalesced u-row loads + 2 NT f loads ----
    // NT on f is essential (R9 A/B): f has zero reuse; letting it allocate
    // evicts u (which is reused) from the caches -> +28% time.
    v4f c4[4]; float m[4];
    #pragma unroll
    for (int k = 0; k < 4; k++) {
        const int li = i0 - 1 + k;                                     // logical row
        const int rc = li < 0 ? 0 : (li > IMG_H - 1 ? IMG_H - 1 : li); // clamped
        c4[k] = *(const v4f*)(ub + (size_t)rc * IMG_W + j0);
        m[k]  = (li >= 1 && li <= IMG_H - 2) ? 1.f : 0.f;  // row interior in v?
    }
    const float* fp = f + img + (size_t)i0 * IMG_W + j0;
    const v4f f0 = __builtin_nontemporal_load((const v4f*)fp);
    const v4f f1 = __builtin_nontemporal_load((const v4f*)(fp + IMG_W));

    // Broadcast weights (L1-cached)
    const float w00 = wt[0], w01 = wt[1], w02 = wt[2];
    const float w10 = wt[3], w11 = wt[4], w12 = wt[5];
    const float w20 = wt[6], w21 = wt[7], w22 = wt[8];
    const float cof = (float)(-(1.0 / 1023.0) * (1.0 / 1023.0) / 4.0);

    // Row-validity masks + Dirichlet column zeros (before any exchange, so
    // every exchanged value is already a valid v-value).
    #pragma unroll
    for (int k = 0; k < 4; k++) {
        c4[k] = c4[k] * m[k];
        if (le) c4[k].x = 0.f;               // col 0 boundary in v
        if (re) c4[k].w = 0.f;               // col 1023 boundary in v
    }

    // ---- Column halos WITHOUT memory loads ----
    // Intra-wave: shuffle from the neighboring lane's registers.
    // Wave-boundary columns (cols 255/256, 511/512, 767/768): 128-B LDS exchange.
    __shared__ float ledge[4][4];            // [wave][k]: lane 0's  .x (span left edge)
    __shared__ float redge[4][4];            // [wave][k]: lane 63's .w (span right edge)
    if (lane == 0) {
        #pragma unroll
        for (int k = 0; k < 4; k++) ledge[wave][k] = c4[k].x;
    }
    if (lane == 63) {
        #pragma unroll
        for (int k = 0; k < 4; k++) redge[wave][k] = c4[k].w;
    }
    __syncthreads();

    float lh[4], rh[4];
    #pragma unroll
    for (int k = 0; k < 4; k++) {
        float l = __shfl_up(c4[k].w, 1);     // col j0-1 from lane-1
        float r = __shfl_down(c4[k].x, 1);   // col j0+4 from lane+1
        if (lane == 0)  l = (wave == 0) ? 0.f : redge[wave - 1][k];
        if (lane == 63) r = (wave == 3) ? 0.f : ledge[wave + 1][k];
        lh[k] = l; rh[k] = r;
    }

    const float keep0 = (i0 >= 1)         ? 1.f : 0.f;   // row i0 interior?
    const float keep1 = (i0 <= IMG_H - 3) ? 1.f : 0.f;   // row i0+1 interior?

    auto stencil = [&](int k, v4f fv, float keep) -> v4f {
        const v4f n = c4[k], cc = c4[k + 1], s = c4[k + 2];
        float r0 = cof * fv.x
                 + w00 * lh[k]     + w01 * n.x  + w02 * n.y
                 + w10 * lh[k + 1] + w11 * cc.x + w12 * cc.y
                 + w20 * lh[k + 2] + w21 * s.x  + w22 * s.y;
        float r1 = cof * fv.y
                 + w00 * n.x  + w01 * n.y  + w02 * n.z
                 + w10 * cc.x + w11 * cc.y + w12 * cc.z
                 + w20 * s.x  + w21 * s.y  + w22 * s.z;
        float r2 = cof * fv.z
                 + w00 * n.y  + w01 * n.z  + w02 * n.w
                 + w10 * cc.y + w11 * cc.z + w12 * cc.w
                 + w20 * s.y  + w21 * s.z  + w22 * s.w;
        float r3 = cof * fv.w
                 + w00 * n.z  + w01 * n.w  + w02 * rh[k]
                 + w10 * cc.z + w11 * cc.w + w12 * rh[k + 1]
                 + w20 * s.z  + w21 * s.w  + w22 * rh[k + 2];
        r0 *= keep; r1 *= keep; r2 *= keep; r3 *= keep;
        if (le) r0 = 0.f;                    // col 0 stays Dirichlet
        if (re) r3 = 0.f;                    // col 1023 stays Dirichlet
        return (v4f){r0, r1, r2, r3};
    };

    const v4f o0 = stencil(0, f0, keep0);
    const v4f o1 = stencil(1, f1, keep1);

    float* ob = out + img + (size_t)i0 * IMG_W + j0;
    __builtin_nontemporal_store(o0, (v4f*)ob);
    __builtin_nontemporal_store(o1, (v4f*)(ob + IMG_W));
}

extern "C" void kernel_launch(void* const* d_in, const int* in_sizes, int n_in,
                              void* d_out, int out_size, void* d_ws, size_t ws_size,
                              hipStream_t stream) {
    const float* u  = (const float*)d_in[0];
    const float* f  = (const float*)d_in[1];
    const float* wt = (const float*)d_in[2];
    float* out = (float*)d_out;

    const int B = 16;
    dim3 grid(B * (IMG_H / 2));   // one block per (batch, row-pair): 8192 blocks
    dim3 block(256);              // 256 threads * 4 cols = 1024-wide rows
    dir_rhs_kernel<<<grid, block, 0, stream>>>(u, f, wt, out);
}